// Round 15
// baseline (296.657 us; speedup 1.0000x reference)
//
#include <hip/hip_runtime.h>

#define NN   40000
#define EE   640000
#define EE2  680000    // EE + NN self loops
#define IND  5
#define ED   11
#define HIDD 128
#define F1   512       // 4 heads * 128
#define NBW  10000     // k_build waves (EE/64)

typedef unsigned short u16;
typedef unsigned int   u32;
typedef __attribute__((ext_vector_type(8))) short bf16x8;
typedef __attribute__((ext_vector_type(4))) float f32x4;

__device__ __forceinline__ float bf2f(u16 u) { return __uint_as_float(((u32)u) << 16); }
__device__ __forceinline__ u16 f2bf(float f) {
    u32 u = __float_as_uint(f);
    return (u16)((u + 0x7FFFu + ((u >> 16) & 1u)) >> 16);   // RNE
}

__device__ __forceinline__ float wsum(float v) {
#pragma unroll
    for (int o = 32; o; o >>= 1) v += __shfl_xor(v, o, 64);
    return v;
}
__device__ __forceinline__ float lrelu(float v) { return v > 0.f ? v : 0.2f * v; }

// edge record (16B, uint4): x=[e0|e1]bf16, y=[e2|e3]bf16, z=src, w=et2(f32 bits).
// dst implicit (records dst-sorted).

// ---------------- init: zero consts + per-dst counters ----------------
__global__ void k_init(float* __restrict__ consts, int* __restrict__ counts) {
    int i = blockIdx.x * blockDim.x + threadIdx.x;
    if (i < 256) consts[i] = 0.f;
    if (i < NN) counts[i] = 0;
}

// consts layout (floats): [0..10] ea col means, [16..59] Be1[k*4+h],
//                         [64..74] Be2[k], [80..83] self1[h], [96] self2
__global__ void k_constsA(float* __restrict__ consts,
                          const float* __restrict__ We1, const float* __restrict__ ae1,
                          const float* __restrict__ We2, const float* __restrict__ ae2) {
    int t = threadIdx.x;  // 64 threads
    if (t < 44) {
        int k = t >> 2, h = t & 3;
        float s = 0.f;
        for (int c = 0; c < HIDD; ++c)
            s += We1[k * F1 + h * HIDD + c] * ae1[h * HIDD + c];
        consts[16 + t] = s;
    }
    if (t >= 48 && t < 48 + ED) {
        int k = t - 48;
        float s = 0.f;
        for (int c = 0; c < HIDD; ++c)
            s += We2[k * HIDD + c] * ae2[c];
        consts[64 + k] = s;
    }
}

__global__ void k_constsB(float* __restrict__ consts) {
    int t = threadIdx.x;  // 64 threads
    __syncthreads();
    if (t < 4) {
        float s = 0.f;
        for (int k = 0; k < ED; ++k) s += consts[k] * consts[16 + k * 4 + t];
        consts[80 + t] = s;
    }
    if (t == 8) {
        float s = 0.f;
        for (int k = 0; k < ED; ++k) s += consts[k] * consts[64 + k];
        consts[96] = s;
    }
}

// ---------------- W2 pre-swizzle into MFMA B-fragment order, split hi/lo bf16 ----
__global__ void k_wswz(const float* __restrict__ W2,
                       u16* __restrict__ bhi, u16* __restrict__ blo) {
    int t = blockIdx.x * blockDim.x + threadIdx.x;   // 8192 = 8nt * 16ks * 64lane
    if (t >= 8192) return;
    int lane = t & 63, ks = (t >> 6) & 15, nt = t >> 10;
    int kbase = ks * 32 + (lane >> 4) * 8;
    int n = nt * 16 + (lane & 15);
    size_t dst = (size_t)t * 8;
#pragma unroll
    for (int j = 0; j < 8; ++j) {
        float v = W2[(size_t)(kbase + j) * HIDD + n];
        u16 h = f2bf(v);
        float resid = v - bf2f(h);
        bhi[dst + j] = h;
        blo[dst + j] = f2bf(resid);
    }
}

// ---------------- CSR: count real edges, persist arrival rank --------------------
__global__ void k_count(const int* __restrict__ ei, int* __restrict__ counts,
                        int* __restrict__ rank) {
    int i = blockIdx.x * blockDim.x + threadIdx.x;
    if (i >= EE) return;
    rank[i] = atomicAdd(&counts[ei[EE + i]], 1);
}

// 3-phase hierarchical exclusive scan of (counts[n]+1) -> row_off
#define SBLK 256
#define SGRID ((NN + SBLK - 1) / SBLK)   // 157
__global__ void __launch_bounds__(SBLK) k_scanA(const int* __restrict__ counts,
                                                int* __restrict__ local_ex,
                                                int* __restrict__ bsum) {
    __shared__ int sh[SBLK];
    int t = threadIdx.x;
    int i = blockIdx.x * SBLK + t;
    int v = (i < NN) ? counts[i] + 1 : 0;    // +1 = self loop
    sh[t] = v;
    __syncthreads();
    for (int o = 1; o < SBLK; o <<= 1) {
        int u = (t >= o) ? sh[t - o] : 0;
        __syncthreads();
        sh[t] += u;
        __syncthreads();
    }
    if (i < NN) local_ex[i] = sh[t] - v;
    if (t == SBLK - 1) bsum[blockIdx.x] = sh[t];
}

__global__ void __launch_bounds__(SBLK) k_scanB(int* __restrict__ bsum,
                                                int* __restrict__ boff) {
    __shared__ int sh[SBLK];
    int t = threadIdx.x;
    int v = (t < SGRID) ? bsum[t] : 0;
    sh[t] = v;
    __syncthreads();
    for (int o = 1; o < SBLK; o <<= 1) {
        int u = (t >= o) ? sh[t - o] : 0;
        __syncthreads();
        sh[t] += u;
        __syncthreads();
    }
    if (t < SGRID) boff[t] = sh[t] - v;
}

__global__ void __launch_bounds__(SBLK) k_scanC(const int* __restrict__ local_ex,
                                                const int* __restrict__ boff,
                                                int* __restrict__ row_off) {
    int t = threadIdx.x;
    int i = blockIdx.x * SBLK + t;
    if (i < NN) row_off[i] = local_ex[i] + boff[blockIdx.x];
    if (i == 0) row_off[NN] = EE2;
}

// ---------------- fused scatter + ea pass: NO GLOBAL ATOMICS AT ALL --------------
// Column sums exit via per-wave partials (plain stores). Theory from rounds
// 10-14: the invariant ~42us across 5 structural variants is the same-line
// atomicAdd(&consts[k]) tail (27.5K serialized RMWs on one 44B line), not the
// record scatter.
__global__ void __launch_bounds__(256) k_build(const float* __restrict__ ea,
                                               const int* __restrict__ ei,
                                               const int* __restrict__ rank,
                                               const int* __restrict__ row_off,
                                               const float* __restrict__ consts,
                                               uint4* __restrict__ rec,
                                               float* __restrict__ psum) {
    int i = blockIdx.x * 256 + threadIdx.x;   // one edge
    int s = ei[i];
    int d = ei[EE + i];
    int pos = row_off[d] + rank[i];
    const float* row = ea + (size_t)i * ED;
    float r[ED];
#pragma unroll
    for (int k = 0; k < ED; ++k) r[k] = row[k];
    float e0 = 0.f, e1 = 0.f, e2 = 0.f, e3 = 0.f, et = 0.f;
#pragma unroll
    for (int k = 0; k < ED; ++k) {
        float a = r[k];
        e0 += a * consts[16 + k * 4 + 0];
        e1 += a * consts[16 + k * 4 + 1];
        e2 += a * consts[16 + k * 4 + 2];
        e3 += a * consts[16 + k * 4 + 3];
        et += a * consts[64 + k];
    }
    uint4 q;
    q.x = (u32)f2bf(e0) | ((u32)f2bf(e1) << 16);
    q.y = (u32)f2bf(e2) | ((u32)f2bf(e3) << 16);
    q.z = (u32)s;
    q.w = __float_as_uint(et);
    rec[pos] = q;
    // per-wave column sums -> plain stores (no atomics)
#pragma unroll
    for (int k = 0; k < ED; ++k) r[k] = wsum(r[k]);   // all lanes hold wave totals
    int wgid = blockIdx.x * 4 + (threadIdx.x >> 6);
    int lane = threadIdx.x & 63;
    if (lane < ED) psum[wgid * ED + lane] = r[lane];
}

// ---------------- reduce per-wave partials -> ea column means --------------------
__global__ void __launch_bounds__(256) k_sumred(const float* __restrict__ psum,
                                                float* __restrict__ consts) {
    __shared__ float sh[256 * 4];   // reuse in 4 chunks of cols
    int t = threadIdx.x;
    float acc[ED];
#pragma unroll
    for (int k = 0; k < ED; ++k) acc[k] = 0.f;
    for (int w = t; w < NBW; w += 256) {
        const float* p = psum + (size_t)w * ED;
#pragma unroll
        for (int k = 0; k < ED; ++k) acc[k] += p[k];
    }
    // block reduce each column via LDS (11 columns, 256 threads)
    for (int k = 0; k < ED; ++k) {
        sh[t] = acc[k];
        __syncthreads();
        for (int o = 128; o; o >>= 1) {
            if (t < o) sh[t] += sh[t + o];
            __syncthreads();
        }
        if (t == 0) consts[k] = sh[0] * (1.0f / (float)EE);   // finalize mean here
        __syncthreads();
    }
}

// ---------------- self-loop records (after constsB), atomic-free -----------------
__global__ void k_self(const int* __restrict__ row_off, const int* __restrict__ counts,
                       const float* __restrict__ consts, uint4* __restrict__ rec) {
    int n = blockIdx.x * blockDim.x + threadIdx.x;
    if (n >= NN) return;
    int pos = row_off[n] + counts[n];        // real edges hold ranks 0..indeg-1
    uint4 q;
    q.x = (u32)f2bf(consts[80]) | ((u32)f2bf(consts[81]) << 16);
    q.y = (u32)f2bf(consts[82]) | ((u32)f2bf(consts[83]) << 16);
    q.z = (u32)n;
    q.w = __float_as_uint(consts[96]);
    rec[pos] = q;
}

// ---------------- layer 1: a_src/a_dst dots, 4 nodes per block -------------------
__global__ void __launch_bounds__(256) k_xh1(const float* __restrict__ x,
                                             const float* __restrict__ W1,
                                             const float* __restrict__ as1,
                                             const float* __restrict__ ad1,
                                             float* __restrict__ aS1,
                                             float* __restrict__ aD1) {
    int n = blockIdx.x * 4 + (threadIdx.x >> 6);
    int t = threadIdx.x & 63;
    int c0 = t * 8, h = t >> 4;
    const float* xp = x + (size_t)n * IND;
    float x0 = xp[0], x1 = xp[1], x2 = xp[2], x3 = xp[3], x4 = xp[4];
    float p = 0.f, q = 0.f;
#pragma unroll
    for (int j = 0; j < 8; ++j) {
        int c = c0 + j;
        float v = x0 * W1[0 * F1 + c] + x1 * W1[1 * F1 + c] + x2 * W1[2 * F1 + c]
                + x3 * W1[3 * F1 + c] + x4 * W1[4 * F1 + c];
        p += v * as1[c];
        q += v * ad1[c];
    }
#pragma unroll
    for (int o = 1; o <= 8; o <<= 1) {     // reduce within 16-lane head group
        p += __shfl_xor(p, o, 64);
        q += __shfl_xor(q, o, 64);
    }
    if ((t & 15) == 0) {
        aS1[n * 4 + h] = p;
        aD1[n * 4 + h] = q;
    }
}

// ---------------- layer 1: single-pass fused score+softmax+agg, 4 nodes/block ----
__global__ void __launch_bounds__(256) k_agg1(const int* __restrict__ row_off,
                                              const uint4* __restrict__ rec,
                                              const float* __restrict__ aS1,
                                              const float* __restrict__ aD1,
                                              const float* __restrict__ x,
                                              const float* __restrict__ W1,
                                              const float* __restrict__ b1,
                                              u16* __restrict__ h1) {
    int n = blockIdx.x * 4 + (threadIdx.x >> 6);
    int t = threadIdx.x & 63;
    int s0 = row_off[n], s1 = row_off[n + 1];
    int h = t & 3;
    float4 adv = *(const float4*)(aD1 + (size_t)n * 4);   // uniform per wave
    float adh = (h == 0) ? adv.x : (h == 1) ? adv.y : (h == 2) ? adv.z : adv.w;
    float z = 0.f, xa0 = 0.f, xa1 = 0.f, xa2 = 0.f, xa3 = 0.f, xa4 = 0.f;
    for (int i = s0 + (t >> 2); i < s1; i += 16) {
        uint4 q = rec[i];
        u32 w2 = (h & 2) ? q.y : q.x;
        float eh = bf2f((h & 1) ? (u16)(w2 >> 16) : (u16)(w2 & 0xFFFF));
        int s = (int)q.z;
        float a = lrelu(eh + aS1[(size_t)s * 4 + h] + adh);
        float ex = __expf(a);
        z += ex;
        const float* xp = x + (size_t)s * IND;
        xa0 += ex * xp[0]; xa1 += ex * xp[1]; xa2 += ex * xp[2];
        xa3 += ex * xp[3]; xa4 += ex * xp[4];
    }
#pragma unroll
    for (int o = 4; o <= 32; o <<= 1) {    // reduce 16 lanes sharing h
        z   += __shfl_xor(z, o, 64);
        xa0 += __shfl_xor(xa0, o, 64); xa1 += __shfl_xor(xa1, o, 64);
        xa2 += __shfl_xor(xa2, o, 64); xa3 += __shfl_xor(xa3, o, 64);
        xa4 += __shfl_xor(xa4, o, 64);
    }
    // redistribute: output head ho = t>>4; lane ho holds head ho's totals (ho&3==ho)
    int ho = t >> 4;
    float zz = __shfl(z, ho);
    float y0 = __shfl(xa0, ho), y1 = __shfl(xa1, ho), y2 = __shfl(xa2, ho);
    float y3 = __shfl(xa3, ho), y4 = __shfl(xa4, ho);
    float ih = 1.f / (zz + 1e-16f);
    int c0 = t * 8;
#pragma unroll
    for (int j = 0; j < 8; ++j) {
        int c = c0 + j;
        float v = (y0 * W1[0 * F1 + c] + y1 * W1[1 * F1 + c] + y2 * W1[2 * F1 + c]
                 + y3 * W1[3 * F1 + c] + y4 * W1[4 * F1 + c]) * ih;
        h1[(size_t)n * F1 + c] = f2bf(fmaxf(v + b1[c], 0.f));
    }
}

// ---------------- layer 2 GEMM (MFMA): xh2(bf16) = h1(bf16) @ W2, fused sd2 ------
__global__ void __launch_bounds__(256, 2) k_gemm2(const u16* __restrict__ h1,
                                                  const u16* __restrict__ bhi,
                                                  const u16* __restrict__ blo,
                                                  const float* __restrict__ as2,
                                                  const float* __restrict__ ad2,
                                                  u16* __restrict__ xh2,
                                                  float* __restrict__ aS2,
                                                  float* __restrict__ aD2) {
    int tid = threadIdx.x;
    int wv = tid >> 6, lane = tid & 63;
    int tile = blockIdx.x * 4 + wv;
    if (tile >= 2500) return;
    int n0 = tile * 16;
    int mrow = lane & 15, quad = lane >> 4;
    const u16* aptr = h1 + (size_t)(n0 + mrow) * F1 + quad * 8;
    const u16* bbase_hi = bhi + lane * 8;
    const u16* bbase_lo = blo + lane * 8;
    f32x4 acc[8];
#pragma unroll
    for (int nt = 0; nt < 8; ++nt) acc[nt] = (f32x4){0.f, 0.f, 0.f, 0.f};

    bf16x8 bh0[8], bl0[8], bh1[8], bl1[8];
    bf16x8 af0, af1;
    af0 = *(const bf16x8*)(aptr);
#pragma unroll
    for (int nt = 0; nt < 8; ++nt) {
        bh0[nt] = *(const bf16x8*)(bbase_hi + nt * 8192);
        bl0[nt] = *(const bf16x8*)(bbase_lo + nt * 8192);
    }
#pragma unroll
    for (int ks = 0; ks < 16; ++ks) {
        if (ks < 15) {
            af1 = *(const bf16x8*)(aptr + (ks + 1) * 32);
#pragma unroll
            for (int nt = 0; nt < 8; ++nt) {
                bh1[nt] = *(const bf16x8*)(bbase_hi + nt * 8192 + (ks + 1) * 512);
                bl1[nt] = *(const bf16x8*)(bbase_lo + nt * 8192 + (ks + 1) * 512);
            }
        }
#pragma unroll
        for (int nt = 0; nt < 8; ++nt) {
            acc[nt] = __builtin_amdgcn_mfma_f32_16x16x32_bf16(af0, bh0[nt], acc[nt], 0, 0, 0);
            acc[nt] = __builtin_amdgcn_mfma_f32_16x16x32_bf16(af0, bl0[nt], acc[nt], 0, 0, 0);
        }
        af0 = af1;
#pragma unroll
        for (int nt = 0; nt < 8; ++nt) { bh0[nt] = bh1[nt]; bl0[nt] = bl1[nt]; }
    }
    // C layout: col = nt*16 + mrow, row = quad*4 + r   (m89-verified)
    float ps[4] = {0.f, 0.f, 0.f, 0.f}, pd[4] = {0.f, 0.f, 0.f, 0.f};
#pragma unroll
    for (int nt = 0; nt < 8; ++nt) {
        int col = nt * 16 + mrow;
        float sa = as2[col], da = ad2[col];
#pragma unroll
        for (int r = 0; r < 4; ++r) {
            float v = acc[nt][r];
            xh2[(size_t)(n0 + quad * 4 + r) * HIDD + col] = f2bf(v);
            ps[r] += v * sa; pd[r] += v * da;
        }
    }
#pragma unroll
    for (int r = 0; r < 4; ++r) {
#pragma unroll
        for (int o = 1; o <= 8; o <<= 1) {
            ps[r] += __shfl_xor(ps[r], o, 64);
            pd[r] += __shfl_xor(pd[r], o, 64);
        }
        if (mrow == 0) {
            aS2[n0 + quad * 4 + r] = ps[r];
            aD2[n0 + quad * 4 + r] = pd[r];
        }
    }
}

// ---------------- layer 2: single-pass score+softmax+agg+FC+sigmoid, 4 nodes/blk -
__global__ void __launch_bounds__(256) k_agg2(const int* __restrict__ row_off,
                                              const uint4* __restrict__ rec,
                                              const float* __restrict__ aS2,
                                              const float* __restrict__ aD2,
                                              const u16* __restrict__ xh2,
                                              const float* __restrict__ bias2,
                                              const float* __restrict__ Wfc,
                                              const float* __restrict__ bfc,
                                              float* __restrict__ out) {
    int n = blockIdx.x * 4 + (threadIdx.x >> 6);
    int t = threadIdx.x & 63;
    int s0 = row_off[n], s1 = row_off[n + 1];
    float adn = aD2[n];                      // uniform per wave
    int g = t >> 4, l = t & 15;
    int c0 = l * 8;
    float z = 0.f;
    float acc[8];
#pragma unroll
    for (int j = 0; j < 8; ++j) acc[j] = 0.f;
    for (int i = s0 + g; i < s1; i += 4) {
        uint4 qe = rec[i];
        int s = (int)qe.z;
        float et2 = __uint_as_float(qe.w);
        float ex = __expf(lrelu(aS2[s] + adn + et2));
        z += ex;
        uint4 q = *(const uint4*)(xh2 + (size_t)s * HIDD + c0);   // 8 bf16
        acc[0] += ex * bf2f((u16)(q.x & 0xFFFF)); acc[1] += ex * bf2f((u16)(q.x >> 16));
        acc[2] += ex * bf2f((u16)(q.y & 0xFFFF)); acc[3] += ex * bf2f((u16)(q.y >> 16));
        acc[4] += ex * bf2f((u16)(q.z & 0xFFFF)); acc[5] += ex * bf2f((u16)(q.z >> 16));
        acc[6] += ex * bf2f((u16)(q.w & 0xFFFF)); acc[7] += ex * bf2f((u16)(q.w >> 16));
    }
    // reduce across the 4 edge subgroups (lanes differing in bits 4,5)
#pragma unroll
    for (int o = 16; o <= 32; o <<= 1) {
        z += __shfl_xor(z, o, 64);
#pragma unroll
        for (int j = 0; j < 8; ++j) acc[j] += __shfl_xor(acc[j], o, 64);
    }
    float inv = 1.f / (z + 1e-16f);
    float p = 0.f;
#pragma unroll
    for (int j = 0; j < 8; ++j) {
        float o = fmaxf(acc[j] * inv + bias2[c0 + j], 0.f);
        p += o * Wfc[c0 + j];
    }
#pragma unroll
    for (int o = 1; o <= 8; o <<= 1) p += __shfl_xor(p, o, 64);
    if (t == 0) {
        float logit = p + bfc[0];
        out[n] = 1.f / (1.f + __expf(-logit));
    }
}

extern "C" void kernel_launch(void* const* d_in, const int* in_sizes, int n_in,
                              void* d_out, int out_size, void* d_ws, size_t ws_size,
                              hipStream_t stream) {
    (void)in_sizes; (void)n_in; (void)out_size; (void)ws_size;
    const float* x   = (const float*)d_in[0];
    const int*   ei  = (const int*)d_in[1];
    const float* ea  = (const float*)d_in[2];
    const float* W1  = (const float*)d_in[3];
    const float* We1 = (const float*)d_in[4];
    const float* as1 = (const float*)d_in[5];
    const float* ad1 = (const float*)d_in[6];
    const float* ae1 = (const float*)d_in[7];
    const float* b1  = (const float*)d_in[8];
    const float* W2  = (const float*)d_in[9];
    const float* We2 = (const float*)d_in[10];
    const float* as2 = (const float*)d_in[11];
    const float* ad2 = (const float*)d_in[12];
    const float* ae2 = (const float*)d_in[13];
    const float* b2v = (const float*)d_in[14];
    const float* Wfc = (const float*)d_in[15];
    const float* bfc = (const float*)d_in[16];
    float* out = (float*)d_out;

    char* ws = (char*)d_ws;
    size_t off = 0;
    auto take = [&](size_t nb) {
        size_t r = off;
        off += (nb + 255) & ~(size_t)255;
        return r;
    };
    float* consts = (float*)(ws + take(1024));
    int* row_off  = (int*)(ws + take((size_t)(NN + 1) * 4));
    int* counts   = (int*)(ws + take((size_t)NN * 4));
    int* local_ex = (int*)(ws + take((size_t)NN * 4));
    int* bsum     = (int*)(ws + take(1024));
    int* boff     = (int*)(ws + take(1024));
    int* rank     = (int*)(ws + take((size_t)EE * 4));
    float* psum   = (float*)(ws + take((size_t)NBW * ED * 4));
    uint4* rec    = (uint4*)(ws + take((size_t)EE2 * 16));
    float* aS1    = (float*)(ws + take((size_t)NN * 16));
    float* aD1    = (float*)(ws + take((size_t)NN * 16));
    float* aS2    = (float*)(ws + take((size_t)NN * 4));
    float* aD2    = (float*)(ws + take((size_t)NN * 4));
    u16* h1       = (u16*)(ws + take((size_t)NN * F1 * 2));
    u16* xh2      = (u16*)(ws + take((size_t)NN * HIDD * 2));
    u16* w2hi     = (u16*)(ws + take((size_t)65536 * 2));
    u16* w2lo     = (u16*)(ws + take((size_t)65536 * 2));

    k_init<<<(NN + 255) / 256, 256, 0, stream>>>(consts, counts);
    k_constsA<<<1, 64, 0, stream>>>(consts, We1, ae1, We2, ae2);
    k_wswz<<<32, 256, 0, stream>>>(W2, w2hi, w2lo);
    k_count<<<(EE + 255) / 256, 256, 0, stream>>>(ei, counts, rank);
    k_scanA<<<SGRID, SBLK, 0, stream>>>(counts, local_ex, bsum);
    k_scanB<<<1, SBLK, 0, stream>>>(bsum, boff);
    k_scanC<<<SGRID, SBLK, 0, stream>>>(local_ex, boff, row_off);

    k_build<<<EE / 256, 256, 0, stream>>>(ea, ei, rank, row_off, consts, rec, psum);
    k_sumred<<<1, 256, 0, stream>>>(psum, consts);
    k_constsB<<<1, 64, 0, stream>>>(consts);
    k_self<<<(NN + 255) / 256, 256, 0, stream>>>(row_off, counts, consts, rec);

    k_xh1<<<NN / 4, 256, 0, stream>>>(x, W1, as1, ad1, aS1, aD1);
    k_agg1<<<NN / 4, 256, 0, stream>>>(row_off, rec, aS1, aD1, x, W1, b1, h1);

    k_gemm2<<<625, 256, 0, stream>>>(h1, w2hi, w2lo, as2, ad2, xh2, aS2, aD2);
    k_agg2<<<NN / 4, 256, 0, stream>>>(row_off, rec, aS2, aD2, xh2, b2v, Wfc, bfc, out);
}

// Round 16
// 295.148 us; speedup vs baseline: 1.0051x; 1.0051x over previous
//
#include <hip/hip_runtime.h>

#define NN   40000
#define EE   640000
#define EE2  680000    // EE + NN self loops
#define IND  5
#define ED   11
#define HIDD 128
#define F1   512       // 4 heads * 128
#define NBW  10000     // k_build waves (EE/64)

typedef unsigned short u16;
typedef unsigned int   u32;
typedef __attribute__((ext_vector_type(8))) short bf16x8;
typedef __attribute__((ext_vector_type(4))) float f32x4;

__device__ __forceinline__ float bf2f(u16 u) { return __uint_as_float(((u32)u) << 16); }
__device__ __forceinline__ u16 f2bf(float f) {
    u32 u = __float_as_uint(f);
    return (u16)((u + 0x7FFFu + ((u >> 16) & 1u)) >> 16);   // RNE
}

__device__ __forceinline__ float wsum(float v) {
#pragma unroll
    for (int o = 32; o; o >>= 1) v += __shfl_xor(v, o, 64);
    return v;
}
__device__ __forceinline__ float lrelu(float v) { return v > 0.f ? v : 0.2f * v; }

// edge record (16B, uint4): x=[e0|e1]bf16, y=[e2|e3]bf16, z=src, w=et2(f32 bits).
// dst implicit (records dst-sorted).

// ---------------- init: zero consts + per-dst counters ----------------
__global__ void k_init(float* __restrict__ consts, int* __restrict__ counts) {
    int i = blockIdx.x * blockDim.x + threadIdx.x;
    if (i < 256) consts[i] = 0.f;
    if (i < NN) counts[i] = 0;
}

// consts layout (floats): [0..10] ea col means, [16..59] Be1[k*4+h],
//                         [64..74] Be2[k], [80..83] self1[h], [96] self2
__global__ void k_constsA(float* __restrict__ consts,
                          const float* __restrict__ We1, const float* __restrict__ ae1,
                          const float* __restrict__ We2, const float* __restrict__ ae2) {
    int t = threadIdx.x;  // 64 threads
    if (t < 44) {
        int k = t >> 2, h = t & 3;
        float s = 0.f;
        for (int c = 0; c < HIDD; ++c)
            s += We1[k * F1 + h * HIDD + c] * ae1[h * HIDD + c];
        consts[16 + t] = s;
    }
    if (t >= 48 && t < 48 + ED) {
        int k = t - 48;
        float s = 0.f;
        for (int c = 0; c < HIDD; ++c)
            s += We2[k * HIDD + c] * ae2[c];
        consts[64 + k] = s;
    }
}

// ---------------- W2 pre-swizzle into MFMA B-fragment order, split hi/lo bf16 ----
__global__ void k_wswz(const float* __restrict__ W2,
                       u16* __restrict__ bhi, u16* __restrict__ blo) {
    int t = blockIdx.x * blockDim.x + threadIdx.x;   // 8192 = 8nt * 16ks * 64lane
    if (t >= 8192) return;
    int lane = t & 63, ks = (t >> 6) & 15, nt = t >> 10;
    int kbase = ks * 32 + (lane >> 4) * 8;
    int n = nt * 16 + (lane & 15);
    size_t dst = (size_t)t * 8;
#pragma unroll
    for (int j = 0; j < 8; ++j) {
        float v = W2[(size_t)(kbase + j) * HIDD + n];
        u16 h = f2bf(v);
        float resid = v - bf2f(h);
        bhi[dst + j] = h;
        blo[dst + j] = f2bf(resid);
    }
}

// ---------------- CSR: count real edges, persist arrival rank --------------------
__global__ void k_count(const int* __restrict__ ei, int* __restrict__ counts,
                        int* __restrict__ rank) {
    int i = blockIdx.x * blockDim.x + threadIdx.x;
    if (i >= EE) return;
    rank[i] = atomicAdd(&counts[ei[EE + i]], 1);
}

// 3-phase hierarchical exclusive scan of (counts[n]+1) -> row_off
#define SBLK 256
#define SGRID ((NN + SBLK - 1) / SBLK)   // 157
__global__ void __launch_bounds__(SBLK) k_scanA(const int* __restrict__ counts,
                                                int* __restrict__ local_ex,
                                                int* __restrict__ bsum) {
    __shared__ int sh[SBLK];
    int t = threadIdx.x;
    int i = blockIdx.x * SBLK + t;
    int v = (i < NN) ? counts[i] + 1 : 0;    // +1 = self loop
    sh[t] = v;
    __syncthreads();
    for (int o = 1; o < SBLK; o <<= 1) {
        int u = (t >= o) ? sh[t - o] : 0;
        __syncthreads();
        sh[t] += u;
        __syncthreads();
    }
    if (i < NN) local_ex[i] = sh[t] - v;
    if (t == SBLK - 1) bsum[blockIdx.x] = sh[t];
}

__global__ void __launch_bounds__(SBLK) k_scanB(int* __restrict__ bsum,
                                                int* __restrict__ boff) {
    __shared__ int sh[SBLK];
    int t = threadIdx.x;
    int v = (t < SGRID) ? bsum[t] : 0;
    sh[t] = v;
    __syncthreads();
    for (int o = 1; o < SBLK; o <<= 1) {
        int u = (t >= o) ? sh[t - o] : 0;
        __syncthreads();
        sh[t] += u;
        __syncthreads();
    }
    if (t < SGRID) boff[t] = sh[t] - v;
}

__global__ void __launch_bounds__(SBLK) k_scanC(const int* __restrict__ local_ex,
                                                const int* __restrict__ boff,
                                                int* __restrict__ row_off) {
    int t = threadIdx.x;
    int i = blockIdx.x * SBLK + t;
    if (i < NN) row_off[i] = local_ex[i] + boff[blockIdx.x];
    if (i == 0) row_off[NN] = EE2;
}

// ---------------- fused scatter + ea pass: no global atomics ---------------------
// Column sums exit via per-wave partials (plain stores); k_sumred reduces them.
__global__ void __launch_bounds__(256) k_build(const float* __restrict__ ea,
                                               const int* __restrict__ ei,
                                               const int* __restrict__ rank,
                                               const int* __restrict__ row_off,
                                               const float* __restrict__ consts,
                                               uint4* __restrict__ rec,
                                               float* __restrict__ psum) {
    int i = blockIdx.x * 256 + threadIdx.x;   // one edge
    int s = ei[i];
    int d = ei[EE + i];
    int pos = row_off[d] + rank[i];
    const float* row = ea + (size_t)i * ED;
    float r[ED];
#pragma unroll
    for (int k = 0; k < ED; ++k) r[k] = row[k];
    float e0 = 0.f, e1 = 0.f, e2 = 0.f, e3 = 0.f, et = 0.f;
#pragma unroll
    for (int k = 0; k < ED; ++k) {
        float a = r[k];
        e0 += a * consts[16 + k * 4 + 0];
        e1 += a * consts[16 + k * 4 + 1];
        e2 += a * consts[16 + k * 4 + 2];
        e3 += a * consts[16 + k * 4 + 3];
        et += a * consts[64 + k];
    }
    uint4 q;
    q.x = (u32)f2bf(e0) | ((u32)f2bf(e1) << 16);
    q.y = (u32)f2bf(e2) | ((u32)f2bf(e3) << 16);
    q.z = (u32)s;
    q.w = __float_as_uint(et);
    rec[pos] = q;
    // per-wave column sums -> plain stores (no atomics)
#pragma unroll
    for (int k = 0; k < ED; ++k) r[k] = wsum(r[k]);   // all lanes hold wave totals
    int wgid = blockIdx.x * 4 + (threadIdx.x >> 6);
    int lane = threadIdx.x & 63;
    if (lane < ED) psum[wgid * ED + lane] = r[lane];
}

// ---------------- reduce partials -> means, then self-loop const terms -----------
// (absorbs the old k_constsB: one launch fewer)
__global__ void __launch_bounds__(256) k_sumred(const float* __restrict__ psum,
                                                float* __restrict__ consts) {
    __shared__ float sh[256];
    __shared__ float mean[ED];
    int t = threadIdx.x;
    float acc[ED];
#pragma unroll
    for (int k = 0; k < ED; ++k) acc[k] = 0.f;
    for (int w = t; w < NBW; w += 256) {
        const float* p = psum + (size_t)w * ED;
#pragma unroll
        for (int k = 0; k < ED; ++k) acc[k] += p[k];
    }
    for (int k = 0; k < ED; ++k) {
        sh[t] = acc[k];
        __syncthreads();
        for (int o = 128; o; o >>= 1) {
            if (t < o) sh[t] += sh[t + o];
            __syncthreads();
        }
        if (t == 0) {
            float m = sh[0] * (1.0f / (float)EE);
            mean[k] = m;
            consts[k] = m;
        }
        __syncthreads();
    }
    if (t < 4) {
        float s = 0.f;
        for (int k = 0; k < ED; ++k) s += mean[k] * consts[16 + k * 4 + t];
        consts[80 + t] = s;
    }
    if (t == 8) {
        float s = 0.f;
        for (int k = 0; k < ED; ++k) s += mean[k] * consts[64 + k];
        consts[96] = s;
    }
}

// ---------------- self-loop records, atomic-free -----------------
__global__ void k_self(const int* __restrict__ row_off, const int* __restrict__ counts,
                       const float* __restrict__ consts, uint4* __restrict__ rec) {
    int n = blockIdx.x * blockDim.x + threadIdx.x;
    if (n >= NN) return;
    int pos = row_off[n] + counts[n];        // real edges hold ranks 0..indeg-1
    uint4 q;
    q.x = (u32)f2bf(consts[80]) | ((u32)f2bf(consts[81]) << 16);
    q.y = (u32)f2bf(consts[82]) | ((u32)f2bf(consts[83]) << 16);
    q.z = (u32)n;
    q.w = __float_as_uint(consts[96]);
    rec[pos] = q;
}

// ---------------- layer 1: a_src/a_dst dots (1 wave per node) --------------------
// 64-thread blocks: round-15 showed 4-node/256-thread batching REGRESSES (+8us;
// block retires at its slowest wave -> coarser scheduling granularity).
__global__ void __launch_bounds__(64) k_xh1(const float* __restrict__ x,
                                            const float* __restrict__ W1,
                                            const float* __restrict__ as1,
                                            const float* __restrict__ ad1,
                                            float* __restrict__ aS1,
                                            float* __restrict__ aD1) {
    int n = blockIdx.x, t = threadIdx.x;
    int c0 = t * 8, h = t >> 4;
    const float* xp = x + (size_t)n * IND;
    float x0 = xp[0], x1 = xp[1], x2 = xp[2], x3 = xp[3], x4 = xp[4];
    float p = 0.f, q = 0.f;
#pragma unroll
    for (int j = 0; j < 8; ++j) {
        int c = c0 + j;
        float v = x0 * W1[0 * F1 + c] + x1 * W1[1 * F1 + c] + x2 * W1[2 * F1 + c]
                + x3 * W1[3 * F1 + c] + x4 * W1[4 * F1 + c];
        p += v * as1[c];
        q += v * ad1[c];
    }
#pragma unroll
    for (int o = 1; o <= 8; o <<= 1) {     // reduce within 16-lane head group
        p += __shfl_xor(p, o, 64);
        q += __shfl_xor(q, o, 64);
    }
    if ((t & 15) == 0) {
        aS1[n * 4 + h] = p;
        aD1[n * 4 + h] = q;
    }
}

// ---------------- layer 1: single-pass fused score+softmax+agg (1 wave/node) -----
__global__ void __launch_bounds__(64) k_agg1(const int* __restrict__ row_off,
                                             const uint4* __restrict__ rec,
                                             const float* __restrict__ aS1,
                                             const float* __restrict__ aD1,
                                             const float* __restrict__ x,
                                             const float* __restrict__ W1,
                                             const float* __restrict__ b1,
                                             u16* __restrict__ h1) {
    int n = blockIdx.x, t = threadIdx.x;
    int s0 = row_off[n], s1 = row_off[n + 1];
    int h = t & 3;
    float4 adv = *(const float4*)(aD1 + (size_t)n * 4);   // uniform
    float adh = (h == 0) ? adv.x : (h == 1) ? adv.y : (h == 2) ? adv.z : adv.w;
    float z = 0.f, xa0 = 0.f, xa1 = 0.f, xa2 = 0.f, xa3 = 0.f, xa4 = 0.f;
    for (int i = s0 + (t >> 2); i < s1; i += 16) {
        uint4 q = rec[i];
        u32 w2 = (h & 2) ? q.y : q.x;
        float eh = bf2f((h & 1) ? (u16)(w2 >> 16) : (u16)(w2 & 0xFFFF));
        int s = (int)q.z;
        float a = lrelu(eh + aS1[(size_t)s * 4 + h] + adh);
        float ex = __expf(a);
        z += ex;
        const float* xp = x + (size_t)s * IND;
        xa0 += ex * xp[0]; xa1 += ex * xp[1]; xa2 += ex * xp[2];
        xa3 += ex * xp[3]; xa4 += ex * xp[4];
    }
#pragma unroll
    for (int o = 4; o <= 32; o <<= 1) {    // reduce 16 lanes sharing h
        z   += __shfl_xor(z, o, 64);
        xa0 += __shfl_xor(xa0, o, 64); xa1 += __shfl_xor(xa1, o, 64);
        xa2 += __shfl_xor(xa2, o, 64); xa3 += __shfl_xor(xa3, o, 64);
        xa4 += __shfl_xor(xa4, o, 64);
    }
    // redistribute: output head ho = t>>4; lane ho holds head ho's totals (ho&3==ho)
    int ho = t >> 4;
    float zz = __shfl(z, ho);
    float y0 = __shfl(xa0, ho), y1 = __shfl(xa1, ho), y2 = __shfl(xa2, ho);
    float y3 = __shfl(xa3, ho), y4 = __shfl(xa4, ho);
    float ih = 1.f / (zz + 1e-16f);
    int c0 = t * 8;
#pragma unroll
    for (int j = 0; j < 8; ++j) {
        int c = c0 + j;
        float v = (y0 * W1[0 * F1 + c] + y1 * W1[1 * F1 + c] + y2 * W1[2 * F1 + c]
                 + y3 * W1[3 * F1 + c] + y4 * W1[4 * F1 + c]) * ih;
        h1[(size_t)n * F1 + c] = f2bf(fmaxf(v + b1[c], 0.f));
    }
}

// ---------------- layer 2 GEMM (MFMA): xh2(bf16) = h1(bf16) @ W2, fused sd2 ------
__global__ void __launch_bounds__(256, 2) k_gemm2(const u16* __restrict__ h1,
                                                  const u16* __restrict__ bhi,
                                                  const u16* __restrict__ blo,
                                                  const float* __restrict__ as2,
                                                  const float* __restrict__ ad2,
                                                  u16* __restrict__ xh2,
                                                  float* __restrict__ aS2,
                                                  float* __restrict__ aD2) {
    int tid = threadIdx.x;
    int wv = tid >> 6, lane = tid & 63;
    int tile = blockIdx.x * 4 + wv;
    if (tile >= 2500) return;
    int n0 = tile * 16;
    int mrow = lane & 15, quad = lane >> 4;
    const u16* aptr = h1 + (size_t)(n0 + mrow) * F1 + quad * 8;
    const u16* bbase_hi = bhi + lane * 8;
    const u16* bbase_lo = blo + lane * 8;
    f32x4 acc[8];
#pragma unroll
    for (int nt = 0; nt < 8; ++nt) acc[nt] = (f32x4){0.f, 0.f, 0.f, 0.f};

    bf16x8 bh0[8], bl0[8], bh1[8], bl1[8];
    bf16x8 af0, af1;
    af0 = *(const bf16x8*)(aptr);
#pragma unroll
    for (int nt = 0; nt < 8; ++nt) {
        bh0[nt] = *(const bf16x8*)(bbase_hi + nt * 8192);
        bl0[nt] = *(const bf16x8*)(bbase_lo + nt * 8192);
    }
#pragma unroll
    for (int ks = 0; ks < 16; ++ks) {
        if (ks < 15) {
            af1 = *(const bf16x8*)(aptr + (ks + 1) * 32);
#pragma unroll
            for (int nt = 0; nt < 8; ++nt) {
                bh1[nt] = *(const bf16x8*)(bbase_hi + nt * 8192 + (ks + 1) * 512);
                bl1[nt] = *(const bf16x8*)(bbase_lo + nt * 8192 + (ks + 1) * 512);
            }
        }
#pragma unroll
        for (int nt = 0; nt < 8; ++nt) {
            acc[nt] = __builtin_amdgcn_mfma_f32_16x16x32_bf16(af0, bh0[nt], acc[nt], 0, 0, 0);
            acc[nt] = __builtin_amdgcn_mfma_f32_16x16x32_bf16(af0, bl0[nt], acc[nt], 0, 0, 0);
        }
        af0 = af1;
#pragma unroll
        for (int nt = 0; nt < 8; ++nt) { bh0[nt] = bh1[nt]; bl0[nt] = bl1[nt]; }
    }
    // C layout: col = nt*16 + mrow, row = quad*4 + r   (m89-verified)
    float ps[4] = {0.f, 0.f, 0.f, 0.f}, pd[4] = {0.f, 0.f, 0.f, 0.f};
#pragma unroll
    for (int nt = 0; nt < 8; ++nt) {
        int col = nt * 16 + mrow;
        float sa = as2[col], da = ad2[col];
#pragma unroll
        for (int r = 0; r < 4; ++r) {
            float v = acc[nt][r];
            xh2[(size_t)(n0 + quad * 4 + r) * HIDD + col] = f2bf(v);
            ps[r] += v * sa; pd[r] += v * da;
        }
    }
#pragma unroll
    for (int r = 0; r < 4; ++r) {
#pragma unroll
        for (int o = 1; o <= 8; o <<= 1) {
            ps[r] += __shfl_xor(ps[r], o, 64);
            pd[r] += __shfl_xor(pd[r], o, 64);
        }
        if (mrow == 0) {
            aS2[n0 + quad * 4 + r] = ps[r];
            aD2[n0 + quad * 4 + r] = pd[r];
        }
    }
}

// ---------------- layer 2: single-pass score+softmax+agg+FC+sigmoid (1 wave/node)
__global__ void __launch_bounds__(64) k_agg2(const int* __restrict__ row_off,
                                             const uint4* __restrict__ rec,
                                             const float* __restrict__ aS2,
                                             const float* __restrict__ aD2,
                                             const u16* __restrict__ xh2,
                                             const float* __restrict__ bias2,
                                             const float* __restrict__ Wfc,
                                             const float* __restrict__ bfc,
                                             float* __restrict__ out) {
    int n = blockIdx.x, t = threadIdx.x;
    int s0 = row_off[n], s1 = row_off[n + 1];
    float adn = aD2[n];                      // uniform
    int g = t >> 4, l = t & 15;
    int c0 = l * 8;
    float z = 0.f;
    float acc[8];
#pragma unroll
    for (int j = 0; j < 8; ++j) acc[j] = 0.f;
    for (int i = s0 + g; i < s1; i += 4) {
        uint4 qe = rec[i];
        int s = (int)qe.z;
        float et2 = __uint_as_float(qe.w);
        float ex = __expf(lrelu(aS2[s] + adn + et2));
        z += ex;
        uint4 q = *(const uint4*)(xh2 + (size_t)s * HIDD + c0);   // 8 bf16
        acc[0] += ex * bf2f((u16)(q.x & 0xFFFF)); acc[1] += ex * bf2f((u16)(q.x >> 16));
        acc[2] += ex * bf2f((u16)(q.y & 0xFFFF)); acc[3] += ex * bf2f((u16)(q.y >> 16));
        acc[4] += ex * bf2f((u16)(q.z & 0xFFFF)); acc[5] += ex * bf2f((u16)(q.z >> 16));
        acc[6] += ex * bf2f((u16)(q.w & 0xFFFF)); acc[7] += ex * bf2f((u16)(q.w >> 16));
    }
    // reduce across the 4 edge subgroups (lanes differing in bits 4,5)
#pragma unroll
    for (int o = 16; o <= 32; o <<= 1) {
        z += __shfl_xor(z, o, 64);
#pragma unroll
        for (int j = 0; j < 8; ++j) acc[j] += __shfl_xor(acc[j], o, 64);
    }
    float inv = 1.f / (z + 1e-16f);
    float p = 0.f;
#pragma unroll
    for (int j = 0; j < 8; ++j) {
        float o = fmaxf(acc[j] * inv + bias2[c0 + j], 0.f);
        p += o * Wfc[c0 + j];
    }
#pragma unroll
    for (int o = 1; o <= 8; o <<= 1) p += __shfl_xor(p, o, 64);
    if (t == 0) {
        float logit = p + bfc[0];
        out[n] = 1.f / (1.f + __expf(-logit));
    }
}

extern "C" void kernel_launch(void* const* d_in, const int* in_sizes, int n_in,
                              void* d_out, int out_size, void* d_ws, size_t ws_size,
                              hipStream_t stream) {
    (void)in_sizes; (void)n_in; (void)out_size; (void)ws_size;
    const float* x   = (const float*)d_in[0];
    const int*   ei  = (const int*)d_in[1];
    const float* ea  = (const float*)d_in[2];
    const float* W1  = (const float*)d_in[3];
    const float* We1 = (const float*)d_in[4];
    const float* as1 = (const float*)d_in[5];
    const float* ad1 = (const float*)d_in[6];
    const float* ae1 = (const float*)d_in[7];
    const float* b1  = (const float*)d_in[8];
    const float* W2  = (const float*)d_in[9];
    const float* We2 = (const float*)d_in[10];
    const float* as2 = (const float*)d_in[11];
    const float* ad2 = (const float*)d_in[12];
    const float* ae2 = (const float*)d_in[13];
    const float* b2v = (const float*)d_in[14];
    const float* Wfc = (const float*)d_in[15];
    const float* bfc = (const float*)d_in[16];
    float* out = (float*)d_out;

    char* ws = (char*)d_ws;
    size_t off = 0;
    auto take = [&](size_t nb) {
        size_t r = off;
        off += (nb + 255) & ~(size_t)255;
        return r;
    };
    float* consts = (float*)(ws + take(1024));
    int* row_off  = (int*)(ws + take((size_t)(NN + 1) * 4));
    int* counts   = (int*)(ws + take((size_t)NN * 4));
    int* local_ex = (int*)(ws + take((size_t)NN * 4));
    int* bsum     = (int*)(ws + take(1024));
    int* boff     = (int*)(ws + take(1024));
    int* rank     = (int*)(ws + take((size_t)EE * 4));
    float* psum   = (float*)(ws + take((size_t)NBW * ED * 4));
    uint4* rec    = (uint4*)(ws + take((size_t)EE2 * 16));
    float* aS1    = (float*)(ws + take((size_t)NN * 16));
    float* aD1    = (float*)(ws + take((size_t)NN * 16));
    float* aS2    = (float*)(ws + take((size_t)NN * 4));
    float* aD2    = (float*)(ws + take((size_t)NN * 4));
    u16* h1       = (u16*)(ws + take((size_t)NN * F1 * 2));
    u16* xh2      = (u16*)(ws + take((size_t)NN * HIDD * 2));
    u16* w2hi     = (u16*)(ws + take((size_t)65536 * 2));
    u16* w2lo     = (u16*)(ws + take((size_t)65536 * 2));

    k_init<<<(NN + 255) / 256, 256, 0, stream>>>(consts, counts);
    k_constsA<<<1, 64, 0, stream>>>(consts, We1, ae1, We2, ae2);
    k_wswz<<<32, 256, 0, stream>>>(W2, w2hi, w2lo);
    k_count<<<(EE + 255) / 256, 256, 0, stream>>>(ei, counts, rank);
    k_scanA<<<SGRID, SBLK, 0, stream>>>(counts, local_ex, bsum);
    k_scanB<<<1, SBLK, 0, stream>>>(bsum, boff);
    k_scanC<<<SGRID, SBLK, 0, stream>>>(local_ex, boff, row_off);

    k_build<<<EE / 256, 256, 0, stream>>>(ea, ei, rank, row_off, consts, rec, psum);
    k_sumred<<<1, 256, 0, stream>>>(psum, consts);
    k_self<<<(NN + 255) / 256, 256, 0, stream>>>(row_off, counts, consts, rec);

    k_xh1<<<NN, 64, 0, stream>>>(x, W1, as1, ad1, aS1, aD1);
    k_agg1<<<NN, 64, 0, stream>>>(row_off, rec, aS1, aD1, x, W1, b1, h1);

    k_gemm2<<<625, 256, 0, stream>>>(h1, w2hi, w2lo, as2, ad2, xh2, aS2, aD2);
    k_agg2<<<NN, 64, 0, stream>>>(row_off, rec, aS2, aD2, xh2, b2v, Wfc, bfc, out);
}

// Round 17
// 282.130 us; speedup vs baseline: 1.0515x; 1.0461x over previous
//
#include <hip/hip_runtime.h>

#define NN   40000
#define EE   640000
#define EE2  680000    // EE + NN self loops
#define IND  5
#define ED   11
#define HIDD 128
#define F1   512       // 4 heads * 128
#define NBW  10000     // k_build waves (EE/64)

typedef unsigned short u16;
typedef unsigned int   u32;
typedef __attribute__((ext_vector_type(8))) short bf16x8;
typedef __attribute__((ext_vector_type(4))) float f32x4;

__device__ __forceinline__ float bf2f(u16 u) { return __uint_as_float(((u32)u) << 16); }
__device__ __forceinline__ u16 f2bf(float f) {
    u32 u = __float_as_uint(f);
    return (u16)((u + 0x7FFFu + ((u >> 16) & 1u)) >> 16);   // RNE
}

__device__ __forceinline__ float wsum(float v) {
#pragma unroll
    for (int o = 32; o; o >>= 1) v += __shfl_xor(v, o, 64);
    return v;
}
__device__ __forceinline__ float lrelu(float v) { return v > 0.f ? v : 0.2f * v; }

// edge record (16B, uint4): x=[e0|e1]bf16, y=[e2|e3]bf16, z=src, w=et2(f32 bits).
// dst implicit (records dst-sorted).

// ---------------- init: zero consts + per-dst counters ----------------
__global__ void k_init(float* __restrict__ consts, int* __restrict__ counts) {
    int i = blockIdx.x * blockDim.x + threadIdx.x;
    if (i < 256) consts[i] = 0.f;
    if (i < NN) counts[i] = 0;
}

// consts layout (floats): [0..10] ea col means, [16..59] Be1[k*4+h],
//                         [64..74] Be2[k], [80..83] self1[h], [96] self2
__global__ void k_constsA(float* __restrict__ consts,
                          const float* __restrict__ We1, const float* __restrict__ ae1,
                          const float* __restrict__ We2, const float* __restrict__ ae2) {
    int t = threadIdx.x;  // 64 threads
    if (t < 44) {
        int k = t >> 2, h = t & 3;
        float s = 0.f;
        for (int c = 0; c < HIDD; ++c)
            s += We1[k * F1 + h * HIDD + c] * ae1[h * HIDD + c];
        consts[16 + t] = s;
    }
    if (t >= 48 && t < 48 + ED) {
        int k = t - 48;
        float s = 0.f;
        for (int c = 0; c < HIDD; ++c)
            s += We2[k * HIDD + c] * ae2[c];
        consts[64 + k] = s;
    }
}

// ---------------- W2 pre-swizzle into MFMA B-fragment order (bf16, single copy) --
// Round 17: lo-residual dropped — h1 is already bf16, W2 rounding is not the
// dominant error term (absmax headroom 2.7x). Halves gemm2 MFMA + B-traffic.
__global__ void k_wswz(const float* __restrict__ W2, u16* __restrict__ bsw) {
    int t = blockIdx.x * blockDim.x + threadIdx.x;   // 8192 = 8nt * 16ks * 64lane
    if (t >= 8192) return;
    int lane = t & 63, ks = (t >> 6) & 15, nt = t >> 10;
    int kbase = ks * 32 + (lane >> 4) * 8;
    int n = nt * 16 + (lane & 15);
    size_t dst = (size_t)t * 8;
#pragma unroll
    for (int j = 0; j < 8; ++j)
        bsw[dst + j] = f2bf(W2[(size_t)(kbase + j) * HIDD + n]);
}

// ---------------- CSR: count real edges, persist arrival rank --------------------
__global__ void k_count(const int* __restrict__ ei, int* __restrict__ counts,
                        int* __restrict__ rank) {
    int i = blockIdx.x * blockDim.x + threadIdx.x;
    if (i >= EE) return;
    rank[i] = atomicAdd(&counts[ei[EE + i]], 1);
}

// 3-phase hierarchical exclusive scan of (counts[n]+1) -> row_off
#define SBLK 256
#define SGRID ((NN + SBLK - 1) / SBLK)   // 157
__global__ void __launch_bounds__(SBLK) k_scanA(const int* __restrict__ counts,
                                                int* __restrict__ local_ex,
                                                int* __restrict__ bsum) {
    __shared__ int sh[SBLK];
    int t = threadIdx.x;
    int i = blockIdx.x * SBLK + t;
    int v = (i < NN) ? counts[i] + 1 : 0;    // +1 = self loop
    sh[t] = v;
    __syncthreads();
    for (int o = 1; o < SBLK; o <<= 1) {
        int u = (t >= o) ? sh[t - o] : 0;
        __syncthreads();
        sh[t] += u;
        __syncthreads();
    }
    if (i < NN) local_ex[i] = sh[t] - v;
    if (t == SBLK - 1) bsum[blockIdx.x] = sh[t];
}

__global__ void __launch_bounds__(SBLK) k_scanB(int* __restrict__ bsum,
                                                int* __restrict__ boff) {
    __shared__ int sh[SBLK];
    int t = threadIdx.x;
    int v = (t < SGRID) ? bsum[t] : 0;
    sh[t] = v;
    __syncthreads();
    for (int o = 1; o < SBLK; o <<= 1) {
        int u = (t >= o) ? sh[t - o] : 0;
        __syncthreads();
        sh[t] += u;
        __syncthreads();
    }
    if (t < SGRID) boff[t] = sh[t] - v;
}

__global__ void __launch_bounds__(SBLK) k_scanC(const int* __restrict__ local_ex,
                                                const int* __restrict__ boff,
                                                int* __restrict__ row_off) {
    int t = threadIdx.x;
    int i = blockIdx.x * SBLK + t;
    if (i < NN) row_off[i] = local_ex[i] + boff[blockIdx.x];
    if (i == 0) row_off[NN] = EE2;
}

// ---------------- fused scatter + ea pass: no global atomics ---------------------
__global__ void __launch_bounds__(256) k_build(const float* __restrict__ ea,
                                               const int* __restrict__ ei,
                                               const int* __restrict__ rank,
                                               const int* __restrict__ row_off,
                                               const float* __restrict__ consts,
                                               uint4* __restrict__ rec,
                                               float* __restrict__ psum) {
    int i = blockIdx.x * 256 + threadIdx.x;   // one edge
    int s = ei[i];
    int d = ei[EE + i];
    int pos = row_off[d] + rank[i];
    const float* row = ea + (size_t)i * ED;
    float r[ED];
#pragma unroll
    for (int k = 0; k < ED; ++k) r[k] = row[k];
    float e0 = 0.f, e1 = 0.f, e2 = 0.f, e3 = 0.f, et = 0.f;
#pragma unroll
    for (int k = 0; k < ED; ++k) {
        float a = r[k];
        e0 += a * consts[16 + k * 4 + 0];
        e1 += a * consts[16 + k * 4 + 1];
        e2 += a * consts[16 + k * 4 + 2];
        e3 += a * consts[16 + k * 4 + 3];
        et += a * consts[64 + k];
    }
    uint4 q;
    q.x = (u32)f2bf(e0) | ((u32)f2bf(e1) << 16);
    q.y = (u32)f2bf(e2) | ((u32)f2bf(e3) << 16);
    q.z = (u32)s;
    q.w = __float_as_uint(et);
    rec[pos] = q;
    // per-wave column sums -> plain stores (no atomics)
#pragma unroll
    for (int k = 0; k < ED; ++k) r[k] = wsum(r[k]);   // all lanes hold wave totals
    int wgid = blockIdx.x * 4 + (threadIdx.x >> 6);
    int lane = threadIdx.x & 63;
    if (lane < ED) psum[wgid * ED + lane] = r[lane];
}

// ---------------- reduce partials -> means, then self-loop const terms -----------
__global__ void __launch_bounds__(256) k_sumred(const float* __restrict__ psum,
                                                float* __restrict__ consts) {
    __shared__ float sh[256];
    __shared__ float mean[ED];
    int t = threadIdx.x;
    float acc[ED];
#pragma unroll
    for (int k = 0; k < ED; ++k) acc[k] = 0.f;
    for (int w = t; w < NBW; w += 256) {
        const float* p = psum + (size_t)w * ED;
#pragma unroll
        for (int k = 0; k < ED; ++k) acc[k] += p[k];
    }
    for (int k = 0; k < ED; ++k) {
        sh[t] = acc[k];
        __syncthreads();
        for (int o = 128; o; o >>= 1) {
            if (t < o) sh[t] += sh[t + o];
            __syncthreads();
        }
        if (t == 0) {
            float m = sh[0] * (1.0f / (float)EE);
            mean[k] = m;
            consts[k] = m;
        }
        __syncthreads();
    }
    if (t < 4) {
        float s = 0.f;
        for (int k = 0; k < ED; ++k) s += mean[k] * consts[16 + k * 4 + t];
        consts[80 + t] = s;
    }
    if (t == 8) {
        float s = 0.f;
        for (int k = 0; k < ED; ++k) s += mean[k] * consts[64 + k];
        consts[96] = s;
    }
}

// ---------------- self-loop records, atomic-free -----------------
__global__ void k_self(const int* __restrict__ row_off, const int* __restrict__ counts,
                       const float* __restrict__ consts, uint4* __restrict__ rec) {
    int n = blockIdx.x * blockDim.x + threadIdx.x;
    if (n >= NN) return;
    int pos = row_off[n] + counts[n];        // real edges hold ranks 0..indeg-1
    uint4 q;
    q.x = (u32)f2bf(consts[80]) | ((u32)f2bf(consts[81]) << 16);
    q.y = (u32)f2bf(consts[82]) | ((u32)f2bf(consts[83]) << 16);
    q.z = (u32)n;
    q.w = __float_as_uint(consts[96]);
    rec[pos] = q;
}

// ---------------- layer 1: a_src/a_dst dots (1 wave per node) --------------------
__global__ void __launch_bounds__(64) k_xh1(const float* __restrict__ x,
                                            const float* __restrict__ W1,
                                            const float* __restrict__ as1,
                                            const float* __restrict__ ad1,
                                            float* __restrict__ aS1,
                                            float* __restrict__ aD1) {
    int n = blockIdx.x, t = threadIdx.x;
    int c0 = t * 8, h = t >> 4;
    const float* xp = x + (size_t)n * IND;
    float x0 = xp[0], x1 = xp[1], x2 = xp[2], x3 = xp[3], x4 = xp[4];
    float p = 0.f, q = 0.f;
#pragma unroll
    for (int j = 0; j < 8; ++j) {
        int c = c0 + j;
        float v = x0 * W1[0 * F1 + c] + x1 * W1[1 * F1 + c] + x2 * W1[2 * F1 + c]
                + x3 * W1[3 * F1 + c] + x4 * W1[4 * F1 + c];
        p += v * as1[c];
        q += v * ad1[c];
    }
#pragma unroll
    for (int o = 1; o <= 8; o <<= 1) {     // reduce within 16-lane head group
        p += __shfl_xor(p, o, 64);
        q += __shfl_xor(q, o, 64);
    }
    if ((t & 15) == 0) {
        aS1[n * 4 + h] = p;
        aD1[n * 4 + h] = q;
    }
}

// ---------------- layer 1: single-pass fused score+softmax+agg (1 wave/node) -----
__global__ void __launch_bounds__(64) k_agg1(const int* __restrict__ row_off,
                                             const uint4* __restrict__ rec,
                                             const float* __restrict__ aS1,
                                             const float* __restrict__ aD1,
                                             const float* __restrict__ x,
                                             const float* __restrict__ W1,
                                             const float* __restrict__ b1,
                                             u16* __restrict__ h1) {
    int n = blockIdx.x, t = threadIdx.x;
    int s0 = row_off[n], s1 = row_off[n + 1];
    int h = t & 3;
    float4 adv = *(const float4*)(aD1 + (size_t)n * 4);   // uniform
    float adh = (h == 0) ? adv.x : (h == 1) ? adv.y : (h == 2) ? adv.z : adv.w;
    float z = 0.f, xa0 = 0.f, xa1 = 0.f, xa2 = 0.f, xa3 = 0.f, xa4 = 0.f;
    for (int i = s0 + (t >> 2); i < s1; i += 16) {
        uint4 q = rec[i];
        u32 w2 = (h & 2) ? q.y : q.x;
        float eh = bf2f((h & 1) ? (u16)(w2 >> 16) : (u16)(w2 & 0xFFFF));
        int s = (int)q.z;
        float a = lrelu(eh + aS1[(size_t)s * 4 + h] + adh);
        float ex = __expf(a);
        z += ex;
        const float* xp = x + (size_t)s * IND;
        xa0 += ex * xp[0]; xa1 += ex * xp[1]; xa2 += ex * xp[2];
        xa3 += ex * xp[3]; xa4 += ex * xp[4];
    }
#pragma unroll
    for (int o = 4; o <= 32; o <<= 1) {    // reduce 16 lanes sharing h
        z   += __shfl_xor(z, o, 64);
        xa0 += __shfl_xor(xa0, o, 64); xa1 += __shfl_xor(xa1, o, 64);
        xa2 += __shfl_xor(xa2, o, 64); xa3 += __shfl_xor(xa3, o, 64);
        xa4 += __shfl_xor(xa4, o, 64);
    }
    // redistribute: output head ho = t>>4; lane ho holds head ho's totals (ho&3==ho)
    int ho = t >> 4;
    float zz = __shfl(z, ho);
    float y0 = __shfl(xa0, ho), y1 = __shfl(xa1, ho), y2 = __shfl(xa2, ho);
    float y3 = __shfl(xa3, ho), y4 = __shfl(xa4, ho);
    float ih = 1.f / (zz + 1e-16f);
    int c0 = t * 8;
#pragma unroll
    for (int j = 0; j < 8; ++j) {
        int c = c0 + j;
        float v = (y0 * W1[0 * F1 + c] + y1 * W1[1 * F1 + c] + y2 * W1[2 * F1 + c]
                 + y3 * W1[3 * F1 + c] + y4 * W1[4 * F1 + c]) * ih;
        h1[(size_t)n * F1 + c] = f2bf(fmaxf(v + b1[c], 0.f));
    }
}

// ---------------- layer 2 GEMM (MFMA): xh2(bf16) = h1(bf16) @ W2(bf16), fused sd2
// Single B stream (lo-residual dropped): 8 MFMA + 8 B-loads per ks.
__global__ void __launch_bounds__(256, 2) k_gemm2(const u16* __restrict__ h1,
                                                  const u16* __restrict__ bsw,
                                                  const float* __restrict__ as2,
                                                  const float* __restrict__ ad2,
                                                  u16* __restrict__ xh2,
                                                  float* __restrict__ aS2,
                                                  float* __restrict__ aD2) {
    int tid = threadIdx.x;
    int wv = tid >> 6, lane = tid & 63;
    int tile = blockIdx.x * 4 + wv;
    if (tile >= 2500) return;
    int n0 = tile * 16;
    int mrow = lane & 15, quad = lane >> 4;
    const u16* aptr = h1 + (size_t)(n0 + mrow) * F1 + quad * 8;
    const u16* bbase = bsw + lane * 8;
    f32x4 acc[8];
#pragma unroll
    for (int nt = 0; nt < 8; ++nt) acc[nt] = (f32x4){0.f, 0.f, 0.f, 0.f};

    bf16x8 b0[8], b1v[8];
    bf16x8 af0, af1;
    af0 = *(const bf16x8*)(aptr);
#pragma unroll
    for (int nt = 0; nt < 8; ++nt)
        b0[nt] = *(const bf16x8*)(bbase + nt * 8192);
#pragma unroll
    for (int ks = 0; ks < 16; ++ks) {
        if (ks < 15) {
            af1 = *(const bf16x8*)(aptr + (ks + 1) * 32);
#pragma unroll
            for (int nt = 0; nt < 8; ++nt)
                b1v[nt] = *(const bf16x8*)(bbase + nt * 8192 + (ks + 1) * 512);
        }
#pragma unroll
        for (int nt = 0; nt < 8; ++nt)
            acc[nt] = __builtin_amdgcn_mfma_f32_16x16x32_bf16(af0, b0[nt], acc[nt], 0, 0, 0);
        af0 = af1;
#pragma unroll
        for (int nt = 0; nt < 8; ++nt) b0[nt] = b1v[nt];
    }
    // C layout: col = nt*16 + mrow, row = quad*4 + r   (m89-verified)
    float ps[4] = {0.f, 0.f, 0.f, 0.f}, pd[4] = {0.f, 0.f, 0.f, 0.f};
#pragma unroll
    for (int nt = 0; nt < 8; ++nt) {
        int col = nt * 16 + mrow;
        float sa = as2[col], da = ad2[col];
#pragma unroll
        for (int r = 0; r < 4; ++r) {
            float v = acc[nt][r];
            xh2[(size_t)(n0 + quad * 4 + r) * HIDD + col] = f2bf(v);
            ps[r] += v * sa; pd[r] += v * da;
        }
    }
#pragma unroll
    for (int r = 0; r < 4; ++r) {
#pragma unroll
        for (int o = 1; o <= 8; o <<= 1) {
            ps[r] += __shfl_xor(ps[r], o, 64);
            pd[r] += __shfl_xor(pd[r], o, 64);
        }
        if (mrow == 0) {
            aS2[n0 + quad * 4 + r] = ps[r];
            aD2[n0 + quad * 4 + r] = pd[r];
        }
    }
}

// ---------------- layer 2: single-pass score+softmax+agg+FC+sigmoid (1 wave/node)
__global__ void __launch_bounds__(64) k_agg2(const int* __restrict__ row_off,
                                             const uint4* __restrict__ rec,
                                             const float* __restrict__ aS2,
                                             const float* __restrict__ aD2,
                                             const u16* __restrict__ xh2,
                                             const float* __restrict__ bias2,
                                             const float* __restrict__ Wfc,
                                             const float* __restrict__ bfc,
                                             float* __restrict__ out) {
    int n = blockIdx.x, t = threadIdx.x;
    int s0 = row_off[n], s1 = row_off[n + 1];
    float adn = aD2[n];                      // uniform
    int g = t >> 4, l = t & 15;
    int c0 = l * 8;
    float z = 0.f;
    float acc[8];
#pragma unroll
    for (int j = 0; j < 8; ++j) acc[j] = 0.f;
    for (int i = s0 + g; i < s1; i += 4) {
        uint4 qe = rec[i];
        int s = (int)qe.z;
        float et2 = __uint_as_float(qe.w);
        float ex = __expf(lrelu(aS2[s] + adn + et2));
        z += ex;
        uint4 q = *(const uint4*)(xh2 + (size_t)s * HIDD + c0);   // 8 bf16
        acc[0] += ex * bf2f((u16)(q.x & 0xFFFF)); acc[1] += ex * bf2f((u16)(q.x >> 16));
        acc[2] += ex * bf2f((u16)(q.y & 0xFFFF)); acc[3] += ex * bf2f((u16)(q.y >> 16));
        acc[4] += ex * bf2f((u16)(q.z & 0xFFFF)); acc[5] += ex * bf2f((u16)(q.z >> 16));
        acc[6] += ex * bf2f((u16)(q.w & 0xFFFF)); acc[7] += ex * bf2f((u16)(q.w >> 16));
    }
    // reduce across the 4 edge subgroups (lanes differing in bits 4,5)
#pragma unroll
    for (int o = 16; o <= 32; o <<= 1) {
        z += __shfl_xor(z, o, 64);
#pragma unroll
        for (int j = 0; j < 8; ++j) acc[j] += __shfl_xor(acc[j], o, 64);
    }
    float inv = 1.f / (z + 1e-16f);
    float p = 0.f;
#pragma unroll
    for (int j = 0; j < 8; ++j) {
        float o = fmaxf(acc[j] * inv + bias2[c0 + j], 0.f);
        p += o * Wfc[c0 + j];
    }
#pragma unroll
    for (int o = 1; o <= 8; o <<= 1) p += __shfl_xor(p, o, 64);
    if (t == 0) {
        float logit = p + bfc[0];
        out[n] = 1.f / (1.f + __expf(-logit));
    }
}

extern "C" void kernel_launch(void* const* d_in, const int* in_sizes, int n_in,
                              void* d_out, int out_size, void* d_ws, size_t ws_size,
                              hipStream_t stream) {
    (void)in_sizes; (void)n_in; (void)out_size; (void)ws_size;
    const float* x   = (const float*)d_in[0];
    const int*   ei  = (const int*)d_in[1];
    const float* ea  = (const float*)d_in[2];
    const float* W1  = (const float*)d_in[3];
    const float* We1 = (const float*)d_in[4];
    const float* as1 = (const float*)d_in[5];
    const float* ad1 = (const float*)d_in[6];
    const float* ae1 = (const float*)d_in[7];
    const float* b1  = (const float*)d_in[8];
    const float* W2  = (const float*)d_in[9];
    const float* We2 = (const float*)d_in[10];
    const float* as2 = (const float*)d_in[11];
    const float* ad2 = (const float*)d_in[12];
    const float* ae2 = (const float*)d_in[13];
    const float* b2v = (const float*)d_in[14];
    const float* Wfc = (const float*)d_in[15];
    const float* bfc = (const float*)d_in[16];
    float* out = (float*)d_out;

    char* ws = (char*)d_ws;
    size_t off = 0;
    auto take = [&](size_t nb) {
        size_t r = off;
        off += (nb + 255) & ~(size_t)255;
        return r;
    };
    float* consts = (float*)(ws + take(1024));
    int* row_off  = (int*)(ws + take((size_t)(NN + 1) * 4));
    int* counts   = (int*)(ws + take((size_t)NN * 4));
    int* local_ex = (int*)(ws + take((size_t)NN * 4));
    int* bsum     = (int*)(ws + take(1024));
    int* boff     = (int*)(ws + take(1024));
    int* rank     = (int*)(ws + take((size_t)EE * 4));
    float* psum   = (float*)(ws + take((size_t)NBW * ED * 4));
    uint4* rec    = (uint4*)(ws + take((size_t)EE2 * 16));
    float* aS1    = (float*)(ws + take((size_t)NN * 16));
    float* aD1    = (float*)(ws + take((size_t)NN * 16));
    float* aS2    = (float*)(ws + take((size_t)NN * 4));
    float* aD2    = (float*)(ws + take((size_t)NN * 4));
    u16* h1       = (u16*)(ws + take((size_t)NN * F1 * 2));
    u16* xh2      = (u16*)(ws + take((size_t)NN * HIDD * 2));
    u16* w2b      = (u16*)(ws + take((size_t)65536 * 2));

    k_init<<<(NN + 255) / 256, 256, 0, stream>>>(consts, counts);
    k_constsA<<<1, 64, 0, stream>>>(consts, We1, ae1, We2, ae2);
    k_wswz<<<32, 256, 0, stream>>>(W2, w2b);
    k_count<<<(EE + 255) / 256, 256, 0, stream>>>(ei, counts, rank);
    k_scanA<<<SGRID, SBLK, 0, stream>>>(counts, local_ex, bsum);
    k_scanB<<<1, SBLK, 0, stream>>>(bsum, boff);
    k_scanC<<<SGRID, SBLK, 0, stream>>>(local_ex, boff, row_off);

    k_build<<<EE / 256, 256, 0, stream>>>(ea, ei, rank, row_off, consts, rec, psum);
    k_sumred<<<1, 256, 0, stream>>>(psum, consts);
    k_self<<<(NN + 255) / 256, 256, 0, stream>>>(row_off, counts, consts, rec);

    k_xh1<<<NN, 64, 0, stream>>>(x, W1, as1, ad1, aS1, aD1);
    k_agg1<<<NN, 64, 0, stream>>>(row_off, rec, aS1, aD1, x, W1, b1, h1);

    k_gemm2<<<625, 256, 0, stream>>>(h1, w2b, as2, ad2, xh2, aS2, aD2);
    k_agg2<<<NN, 64, 0, stream>>>(row_off, rec, aS2, aD2, xh2, b2v, Wfc, bfc, out);
}